// Round 1
// baseline (2895.674 us; speedup 1.0000x reference)
//
#include <hip/hip_runtime.h>
#include <math.h>

// Problem constants (fixed by reference):
// C=48, DM=24, DIN=48, DS=8, DC=4, DTR=2, B=2, D=H=W=32, L=32768
#define LL   32768
#define NCH  1024          // number of scan chunks per sequence
#define LC   32            // chunk length (NCH*LC == LL)
#define BL48 3145728       // B*48*L floats
#define BL8  524288        // B*8*L floats
#define PSZ  786432        // per-plane per-dir: B*48*8*NCH

// permuted sequence index l -> physical spatial offset (within a [32,32,32] cube)
__device__ __forceinline__ int pmap(int l, int orient){
  if (orient == 0) return l;                 // (d,h,w) order, identity
  int a = l & 31, rem = l >> 5;
  int b2 = rem & 31, c2 = rem >> 5;
  if (orient == 1) return a*1024 + c2*32 + b2;   // l=(h,w,d) -> phys d*1024+h*32+w
  return b2*1024 + a*32 + c2;                    // l=(w,d,h) -> phys d*1024+h*32+w
}

__device__ __forceinline__ float sigmoidf_(float x){ return 1.0f/(1.0f+__expf(-x)); }
__device__ __forceinline__ float softplusf_(float x){ return (x > 20.0f) ? x : log1pf(__expf(x)); }

// Fused: gather(permute) + LayerNorm + in_proj + causal conv1d + silu + x_proj + dt(softplus)
// for BOTH directions. Backward dir writes at flipped index lb = L-1-l.
// Outputs (planar [b][ch][pos], dir b at +BL48/+BL8): dtbuf, xcbuf, zbuf(raw z), Bmbuf, Cmbuf.
extern "C" __global__ void __launch_bounds__(128)
k_inconv(const float* __restrict__ cur,
         const float* __restrict__ lng, const float* __restrict__ lnb,
         const float* __restrict__ in_w, const float* __restrict__ conv_w,
         const float* __restrict__ conv_b, const float* __restrict__ xproj_w,
         const float* __restrict__ dt_w, const float* __restrict__ dt_b,
         float* __restrict__ dtbuf, float* __restrict__ xcbuf, float* __restrict__ zbuf,
         float* __restrict__ Bmbuf, float* __restrict__ Cmbuf, int orient)
{
  // xz (pre-conv) rows for l = bs-3 .. bs+130  (128 own rows + 3 halo each side)
  __shared__ float xzf[134][49];   // stride 49 -> conflict-free for stride-48 access
  __shared__ float xzb[134][49];
  const int tid = threadIdx.x;
  const int b   = blockIdx.y;
  const int bs  = blockIdx.x * 128;
  const int jf = 2*orient, jb = jf + 1;
  const float* iwf = in_w + jf*2304;   // (96,24)
  const float* iwb = in_w + jb*2304;

  for (int r = tid; r < 134; r += 128) {
    int l = bs - 3 + r;
    float uf[24], ub[24];
    if (l >= 0 && l < LL) {
      int phys = pmap(l, orient);
      const float* p = cur + (size_t)b*48*LL + phys;
      float v[48]; float mu = 0.f;
      #pragma unroll
      for (int c2 = 0; c2 < 48; c2++){ v[c2] = p[(size_t)c2*LL]; mu += v[c2]; }
      mu *= (1.f/48.f);
      float var = 0.f;
      #pragma unroll
      for (int c2 = 0; c2 < 48; c2++){ float dd = v[c2]-mu; var += dd*dd; }
      float rstd = rsqrtf(var*(1.f/48.f) + 1e-5f);
      #pragma unroll
      for (int c2 = 0; c2 < 24; c2++){
        uf[c2] = (v[c2]   -mu)*rstd*lng[c2]    + lnb[c2];
        ub[c2] = (v[c2+24]-mu)*rstd*lng[c2+24] + lnb[c2+24];
      }
    } else {
      #pragma unroll
      for (int c2 = 0; c2 < 24; c2++){ uf[c2]=0.f; ub[c2]=0.f; }
    }
    const bool own = (r >= 3 && r < 131);   // own rows are always valid l
    const int l_f = l, l_b = LL-1-l;
    for (int e = 0; e < 96; e++){
      float af = 0.f, ab = 0.f;
      #pragma unroll
      for (int d = 0; d < 24; d++){
        af += uf[d]*iwf[e*24+d];
        ab += ub[d]*iwb[e*24+d];
      }
      if (e < 48) { xzf[r][e] = af; xzb[r][e] = ab; }
      else if (own) {
        zbuf[(size_t)(b*48+(e-48))*LL + l_f] = af;
        zbuf[(size_t)BL48 + (size_t)(b*48+(e-48))*LL + l_b] = ab;
      }
    }
  }
  __syncthreads();

  const int l  = bs + tid;
  const int lb = LL-1-l;
  const float* cwf = conv_w + jf*192;  const float* cwb = conv_w + jb*192;   // (48,4)
  const float* cbf = conv_b + jf*48;   const float* cbb = conv_b + jb*48;
  const float* xwf = xproj_w + jf*864; const float* xwb = xproj_w + jb*864;  // (18,48)
  float xdf[18], xdb[18];
  #pragma unroll
  for (int j = 0; j < 18; j++){ xdf[j]=0.f; xdb[j]=0.f; }
  for (int d = 0; d < 48; d++){
    float accf = cbf[d], accb = cbb[d];
    #pragma unroll
    for (int k = 0; k < 4; k++){
      // fwd: xc[l] = sum_k xz[l+k-3]*cw[k]  -> rows tid..tid+3
      accf += xzf[tid+k][d]   * cwf[d*4+k];
      // bwd: backward pos lb needs bwd-xz at lb+k-3 -> natural l+3-k -> row tid+6-k
      accb += xzb[tid+6-k][d] * cwb[d*4+k];
    }
    accf = accf * sigmoidf_(accf);   // silu
    accb = accb * sigmoidf_(accb);
    xcbuf[(size_t)(b*48+d)*LL + l]                  = accf;
    xcbuf[(size_t)BL48 + (size_t)(b*48+d)*LL + lb]  = accb;
    #pragma unroll
    for (int j = 0; j < 18; j++){
      xdf[j] += accf*xwf[j*48+d];
      xdb[j] += accb*xwb[j*48+d];
    }
  }
  const float* dwf = dt_w + jf*96; const float* dwb = dt_w + jb*96;   // (48,2)
  const float* dbf = dt_b + jf*48; const float* dbb = dt_b + jb*48;
  for (int d = 0; d < 48; d++){
    float tf = xdf[0]*dwf[d*2] + xdf[1]*dwf[d*2+1] + dbf[d];
    float tb = xdb[0]*dwb[d*2] + xdb[1]*dwb[d*2+1] + dbb[d];
    dtbuf[(size_t)(b*48+d)*LL + l]                 = softplusf_(tf);
    dtbuf[(size_t)BL48 + (size_t)(b*48+d)*LL + lb] = softplusf_(tb);
  }
  #pragma unroll
  for (int s = 0; s < 8; s++){
    Bmbuf[(size_t)(b*8+s)*LL + l] = xdf[2+s];
    Cmbuf[(size_t)(b*8+s)*LL + l] = xdf[10+s];
    Bmbuf[(size_t)BL8 + (size_t)(b*8+s)*LL + lb] = xdb[2+s];
    Cmbuf[(size_t)BL8 + (size_t)(b*8+s)*LL + lb] = xdb[10+s];
  }
}

// Scan phase 1: per (dir,b,d,chunk) compute P = prod(dA), S = local scan from h=0, for s=0..7.
extern "C" __global__ void __launch_bounds__(256)
k_scan1(const float* __restrict__ dtbuf, const float* __restrict__ xcbuf,
        const float* __restrict__ Bmbuf, const float* __restrict__ A_log,
        float* __restrict__ PS, int orient)
{
  const int dir = blockIdx.y;
  const float* dt = dtbuf + (size_t)dir*BL48;
  const float* xc = xcbuf + (size_t)dir*BL48;
  const float* Bm = Bmbuf + (size_t)dir*BL8;
  float* ps = PS + (size_t)dir*2*PSZ;
  int t = blockIdx.x*256 + threadIdx.x;
  int c = t & (NCH-1);
  int q = t >> 10; int d = q % 48; int b = q / 48;
  const float* Al = A_log + (2*orient+dir)*384 + d*8;
  float A[8], P[8], S[8];
  #pragma unroll
  for (int s = 0; s < 8; s++){ A[s] = -__expf(Al[s]); P[s]=1.f; S[s]=0.f; }
  const float* pdt = dt + (size_t)(b*48+d)*LL + c*LC;
  const float* pxc = xc + (size_t)(b*48+d)*LL + c*LC;
  const float* pBm = Bm + (size_t)b*8*LL + c*LC;
  for (int j = 0; j < LC; j++){
    float dtv = pdt[j], xcv = pxc[j];
    float dx = dtv*xcv;
    #pragma unroll
    for (int s = 0; s < 8; s++){
      float dA = __expf(dtv*A[s]);
      P[s] *= dA;
      S[s] = S[s]*dA + dx*pBm[(size_t)s*LL + j];
    }
  }
  int base = ((b*48+d)*8)*NCH + c;
  #pragma unroll
  for (int s = 0; s < 8; s++){
    ps[base + s*NCH]       = P[s];
    ps[PSZ + base + s*NCH] = S[s];
  }
}

// Scan phase 2: sequential combine over chunks; overwrite S-plane with h_start per chunk.
extern "C" __global__ void __launch_bounds__(256)
k_scan2(float* __restrict__ PS)
{
  int t = blockIdx.x*256 + threadIdx.x;
  if (t >= 1536) return;                 // 2 dirs * B*48*8
  int dir = t / 768, r = t % 768;
  float* Pp = PS + (size_t)dir*2*PSZ + (size_t)r*NCH;
  float* Sp = Pp + PSZ;
  float h = 0.f;
  for (int c = 0; c < NCH; c++){
    float p = Pp[c], sE = Sp[c];
    Sp[c] = h;                            // h at chunk start
    h = p*h + sE;
  }
}

// Scan phase 3: replay with correct h0; fuse y = h.C + xc*Dp, gate y *= silu(z);
// writes gated y in-place over zbuf.
extern "C" __global__ void __launch_bounds__(256)
k_scan3(const float* __restrict__ dtbuf, const float* __restrict__ xcbuf,
        float* __restrict__ zbuf, const float* __restrict__ Bmbuf,
        const float* __restrict__ Cmbuf, const float* __restrict__ A_log,
        const float* __restrict__ Dp, const float* __restrict__ PS, int orient)
{
  const int dir = blockIdx.y;
  const float* dt = dtbuf + (size_t)dir*BL48;
  const float* xc = xcbuf + (size_t)dir*BL48;
  float* z = zbuf + (size_t)dir*BL48;
  const float* Bm = Bmbuf + (size_t)dir*BL8;
  const float* Cm = Cmbuf + (size_t)dir*BL8;
  const float* ps = PS + (size_t)dir*2*PSZ;
  int t = blockIdx.x*256 + threadIdx.x;
  int c = t & (NCH-1);
  int q = t >> 10; int d = q % 48; int b = q / 48;
  const float* Al = A_log + (2*orient+dir)*384 + d*8;
  int base = ((b*48+d)*8)*NCH + c;
  float A[8], h[8];
  #pragma unroll
  for (int s = 0; s < 8; s++){
    A[s] = -__expf(Al[s]);
    h[s] = ps[PSZ + base + s*NCH];
  }
  float Dpd = Dp[(2*orient+dir)*48 + d];
  const float* pdt = dt + (size_t)(b*48+d)*LL + c*LC;
  const float* pxc = xc + (size_t)(b*48+d)*LL + c*LC;
  float* pz = z + (size_t)(b*48+d)*LL + c*LC;
  const float* pBm = Bm + (size_t)b*8*LL + c*LC;
  const float* pCm = Cm + (size_t)b*8*LL + c*LC;
  for (int j = 0; j < LC; j++){
    float dtv = pdt[j], xcv = pxc[j], zv = pz[j];
    float dx = dtv*xcv;
    float y = 0.f;
    #pragma unroll
    for (int s = 0; s < 8; s++){
      float dA = __expf(dtv*A[s]);
      h[s] = h[s]*dA + dx*pBm[(size_t)s*LL + j];
      y += h[s]*pCm[(size_t)s*LL + j];
    }
    y += xcv*Dpd;
    pz[j] = y * (zv * sigmoidf_(zv));
  }
}

// out-proj both dirs + un-flip backward + residual (+x on last orientation),
// scatter back to physical (B,C,D,H,W) layout.
extern "C" __global__ void __launch_bounds__(256)
k_combine(const float* __restrict__ zbuf, const float* __restrict__ out_w,
          const float* __restrict__ cur, const float* __restrict__ x_in,
          float* __restrict__ outp, int orient, int addx)
{
  int tid = threadIdx.x;
  int b = blockIdx.y;
  int l = blockIdx.x*256 + tid;
  int lb = LL-1-l;
  const float* owf = out_w + (size_t)(2*orient)*1152;    // (24,48)
  const float* owb = out_w + (size_t)(2*orient+1)*1152;
  float of[24], ob[24];
  #pragma unroll
  for (int e = 0; e < 24; e++){ of[e]=0.f; ob[e]=0.f; }
  for (int d = 0; d < 48; d++){
    float yf = zbuf[(size_t)(b*48+d)*LL + l];
    float yb = zbuf[(size_t)BL48 + (size_t)(b*48+d)*LL + lb];
    #pragma unroll
    for (int e = 0; e < 24; e++){
      of[e] += yf*owf[e*48+d];
      ob[e] += yb*owb[e*48+d];
    }
  }
  int phys = pmap(l, orient);
  size_t pb = (size_t)b*48*LL + phys;
  #pragma unroll
  for (int c2 = 0; c2 < 48; c2++){
    float val = (c2 < 24 ? of[c2] : ob[c2-24]) + cur[pb + (size_t)c2*LL];
    if (addx) val += x_in[pb + (size_t)c2*LL];
    outp[pb + (size_t)c2*LL] = val;
  }
}

extern "C" void kernel_launch(void* const* d_in, const int* in_sizes, int n_in,
                              void* d_out, int out_size, void* d_ws, size_t ws_size,
                              hipStream_t stream)
{
  const float* x       = (const float*)d_in[0];
  const float* ln_g    = (const float*)d_in[1];
  const float* ln_b    = (const float*)d_in[2];
  const float* in_w    = (const float*)d_in[3];
  const float* conv_w  = (const float*)d_in[4];
  const float* conv_b  = (const float*)d_in[5];
  const float* xproj_w = (const float*)d_in[6];
  const float* dt_w    = (const float*)d_in[7];
  const float* dt_b    = (const float*)d_in[8];
  const float* A_log   = (const float*)d_in[9];
  const float* Dp      = (const float*)d_in[10];
  const float* out_w   = (const float*)d_in[11];
  float* out = (float*)d_out;

  float* ws   = (float*)d_ws;
  float* dtb  = ws;                          // 2*BL48
  float* xcb  = dtb + 2*(size_t)BL48;        // 2*BL48
  float* zb   = xcb + 2*(size_t)BL48;        // 2*BL48 (becomes gated y in scan3)
  float* Bmb  = zb  + 2*(size_t)BL48;        // 2*BL8
  float* Cmb  = Bmb + 2*(size_t)BL8;         // 2*BL8
  float* PS   = Cmb + 2*(size_t)BL8;         // 2 dirs * 2 planes * PSZ
  float* cur1 = PS  + 4*(size_t)PSZ;         // BL48
  float* cur2 = cur1 + (size_t)BL48;         // BL48
  // total: ~121.6 MB of workspace

  const float* curp[3] = {x, cur1, cur2};
  float*       nxt[3]  = {cur1, cur2, out};

  for (int i = 0; i < 3; i++){
    k_inconv<<<dim3(LL/128, 2), 128, 0, stream>>>(curp[i], ln_g + i*48, ln_b + i*48,
        in_w, conv_w, conv_b, xproj_w, dt_w, dt_b, dtb, xcb, zb, Bmb, Cmb, i);
    k_scan1<<<dim3(384, 2), 256, 0, stream>>>(dtb, xcb, Bmb, A_log, PS, i);
    k_scan2<<<dim3(6), 256, 0, stream>>>(PS);
    k_scan3<<<dim3(384, 2), 256, 0, stream>>>(dtb, xcb, zb, Bmb, Cmb, A_log, Dp, PS, i);
    k_combine<<<dim3(LL/256, 2), 256, 0, stream>>>(zb, out_w, curp[i], x, nxt[i], i, (i==2)?1:0);
  }
}

// Round 2
// 1082.520 us; speedup vs baseline: 2.6749x; 2.6749x over previous
//
#include <hip/hip_runtime.h>
#include <math.h>

// C=48, DM=24, DIN=48, DS=8, DC=4, DTR=2, B=2, D=H=W=32, L=32768
#define LL   32768
#define NCH  1024          // scan chunks per sequence
#define LC   32            // chunk length
#define BL48 3145728       // B*48*L floats (one dir, planar)  == 2*48*LL
#define ROW48(g,l) (((size_t)(g)*LL + (l))*48)
#define ROW16(g,l) (((size_t)(g)*LL + (l))*16)

__device__ __forceinline__ float sigmoidf_(float x){ return 1.0f/(1.0f+__expf(-x)); }
__device__ __forceinline__ float softplusf_(float x){ return (x > 20.0f) ? x : log1pf(__expf(x)); }

// ---------------------------------------------------------------------------
// Fused LN + in-proj + causal conv + silu + x-proj + dt(softplus), both dirs.
// Input cur: l-space planar [b][48][l]. Outputs row-major per position:
//   dtb/xcb/zb: [g][l][48], BCB: [g][l][16] (B in 0..7, C in 8..15), g=dir*2+b.
// Backward dir (g=2+b) written at flipped position lb = LL-1-l.
// ---------------------------------------------------------------------------
extern "C" __global__ void __launch_bounds__(128)
k_inconv(const float* __restrict__ cur,
         const float* __restrict__ lng, const float* __restrict__ lnb,
         const float* __restrict__ in_w, const float* __restrict__ conv_w,
         const float* __restrict__ conv_b, const float* __restrict__ xproj_w,
         const float* __restrict__ dt_w, const float* __restrict__ dt_b,
         float* __restrict__ dtb, float* __restrict__ xcb, float* __restrict__ zb,
         float* __restrict__ BCB, int orient)
{
  __shared__ float xzf[134][49];
  __shared__ float xzb[134][49];
  const int tid = threadIdx.x;
  const int b   = blockIdx.y;
  const int bs  = blockIdx.x * 128;
  const int jf = 2*orient, jb = jf + 1;
  const int G0 = b, G1 = 2 + b;
  const float* iwf = in_w + jf*2304;   // (96,24)
  const float* iwb = in_w + jb*2304;

  for (int r = tid; r < 134; r += 128) {
    int l = bs - 3 + r;
    float uf[24], ub[24];
    if (l >= 0 && l < LL) {
      const float* p = cur + (size_t)b*48*LL + l;
      float v[48]; float mu = 0.f;
      #pragma unroll
      for (int c2 = 0; c2 < 48; c2++){ v[c2] = p[(size_t)c2*LL]; mu += v[c2]; }
      mu *= (1.f/48.f);
      float var = 0.f;
      #pragma unroll
      for (int c2 = 0; c2 < 48; c2++){ float dd = v[c2]-mu; var += dd*dd; }
      float rstd = rsqrtf(var*(1.f/48.f) + 1e-5f);
      #pragma unroll
      for (int c2 = 0; c2 < 24; c2++){
        uf[c2] = (v[c2]   -mu)*rstd*lng[c2]    + lnb[c2];
        ub[c2] = (v[c2+24]-mu)*rstd*lng[c2+24] + lnb[c2+24];
      }
    } else {
      #pragma unroll
      for (int c2 = 0; c2 < 24; c2++){ uf[c2]=0.f; ub[c2]=0.f; }
    }
    // x-half of in-proj -> LDS (rows with halo)
    for (int e = 0; e < 48; e++){
      float af = 0.f, ab = 0.f;
      #pragma unroll
      for (int d = 0; d < 24; d++){
        af += uf[d]*iwf[e*24+d];
        ab += ub[d]*iwb[e*24+d];
      }
      xzf[r][e] = af; xzb[r][e] = ab;
    }
    // z-half -> global rows (own rows only), grouped float4
    if (r >= 3 && r < 131){
      const int lb2 = LL-1-l;
      float* zf = zb + ROW48(G0, l);
      float* zbk = zb + ROW48(G1, lb2);
      for (int e0 = 48; e0 < 96; e0 += 4){
        float af[4], ab[4];
        #pragma unroll
        for (int k = 0; k < 4; k++){
          float sf = 0.f, sb = 0.f;
          #pragma unroll
          for (int d = 0; d < 24; d++){
            sf += uf[d]*iwf[(e0+k)*24+d];
            sb += ub[d]*iwb[(e0+k)*24+d];
          }
          af[k]=sf; ab[k]=sb;
        }
        *(float4*)(zf  + (e0-48)) = make_float4(af[0],af[1],af[2],af[3]);
        *(float4*)(zbk + (e0-48)) = make_float4(ab[0],ab[1],ab[2],ab[3]);
      }
    }
  }
  __syncthreads();

  const int l  = bs + tid;
  const int lb2 = LL-1-l;
  const float* cwf = conv_w + jf*192;  const float* cwb = conv_w + jb*192;   // (48,4)
  const float* cbf = conv_b + jf*48;   const float* cbb = conv_b + jb*48;
  const float* xwf = xproj_w + jf*864; const float* xwb = xproj_w + jb*864;  // (18,48)
  float xdf[18], xdb[18];
  #pragma unroll
  for (int j = 0; j < 18; j++){ xdf[j]=0.f; xdb[j]=0.f; }
  float* xcf = xcb + ROW48(G0, l);
  float* xcbk = xcb + ROW48(G1, lb2);
  for (int d0 = 0; d0 < 48; d0 += 4){
    float vf[4], vb[4];
    #pragma unroll
    for (int k = 0; k < 4; k++){
      int d = d0 + k;
      float accf = cbf[d], accb = cbb[d];
      #pragma unroll
      for (int kk = 0; kk < 4; kk++){
        accf += xzf[tid+kk][d]   * cwf[d*4+kk];
        accb += xzb[tid+6-kk][d] * cwb[d*4+kk];
      }
      accf = accf * sigmoidf_(accf);
      accb = accb * sigmoidf_(accb);
      vf[k] = accf; vb[k] = accb;
      #pragma unroll
      for (int j = 0; j < 18; j++){
        xdf[j] += accf*xwf[j*48+d];
        xdb[j] += accb*xwb[j*48+d];
      }
    }
    *(float4*)(xcf  + d0) = make_float4(vf[0],vf[1],vf[2],vf[3]);
    *(float4*)(xcbk + d0) = make_float4(vb[0],vb[1],vb[2],vb[3]);
  }
  // dt rows
  const float* dwf = dt_w + jf*96; const float* dwb = dt_w + jb*96;   // (48,2)
  const float* dbf = dt_b + jf*48; const float* dbb = dt_b + jb*48;
  float* dtf = dtb + ROW48(G0, l);
  float* dtbk = dtb + ROW48(G1, lb2);
  for (int d0 = 0; d0 < 48; d0 += 4){
    float vf[4], vb[4];
    #pragma unroll
    for (int k = 0; k < 4; k++){
      int d = d0 + k;
      vf[k] = softplusf_(xdf[0]*dwf[d*2] + xdf[1]*dwf[d*2+1] + dbf[d]);
      vb[k] = softplusf_(xdb[0]*dwb[d*2] + xdb[1]*dwb[d*2+1] + dbb[d]);
    }
    *(float4*)(dtf  + d0) = make_float4(vf[0],vf[1],vf[2],vf[3]);
    *(float4*)(dtbk + d0) = make_float4(vb[0],vb[1],vb[2],vb[3]);
  }
  // B/C rows (B = xdf[2..9], C = xdf[10..17])
  float* bcf = BCB + ROW16(G0, l);
  float* bcbk = BCB + ROW16(G1, lb2);
  *(float4*)(bcf+0)  = make_float4(xdf[2],xdf[3],xdf[4],xdf[5]);
  *(float4*)(bcf+4)  = make_float4(xdf[6],xdf[7],xdf[8],xdf[9]);
  *(float4*)(bcf+8)  = make_float4(xdf[10],xdf[11],xdf[12],xdf[13]);
  *(float4*)(bcf+12) = make_float4(xdf[14],xdf[15],xdf[16],xdf[17]);
  *(float4*)(bcbk+0)  = make_float4(xdb[2],xdb[3],xdb[4],xdb[5]);
  *(float4*)(bcbk+4)  = make_float4(xdb[6],xdb[7],xdb[8],xdb[9]);
  *(float4*)(bcbk+8)  = make_float4(xdb[10],xdb[11],xdb[12],xdb[13]);
  *(float4*)(bcbk+12) = make_float4(xdb[14],xdb[15],xdb[16],xdb[17]);
}

// ---------------------------------------------------------------------------
// Scan phase 1: lane = d (48 per stream), 4 streams per block (block=192).
// Per (g, chunk): P[s]=prod dA, S[s]=local scan from 0. PS layout [g][c][768]:
// P at [d*8+s], S at [384+d*8+s].
// ---------------------------------------------------------------------------
extern "C" __global__ void __launch_bounds__(192)
k_scan1(const float* __restrict__ dtb, const float* __restrict__ xcb,
        const float* __restrict__ BCB, const float* __restrict__ A_log,
        float* __restrict__ PS, int orient)
{
  const int d = threadIdx.x % 48;
  const int sid = blockIdx.x*4 + threadIdx.x/48;
  const int c = sid & (NCH-1);
  const int g = sid >> 10;          // dir*2 + b
  const int dir = g >> 1;
  const float* Al = A_log + (2*orient+dir)*384 + d*8;
  float A[8], P[8], S[8];
  #pragma unroll
  for (int s = 0; s < 8; s++){ A[s] = -__expf(Al[s]); P[s]=1.f; S[s]=0.f; }
  const float* pdt = dtb + ROW48(g, c*LC) + d;
  const float* pxc = xcb + ROW48(g, c*LC) + d;
  const float* pbc = BCB + ROW16(g, c*LC);
  #pragma unroll 4
  for (int j = 0; j < LC; j++){
    float dtv = pdt[(size_t)j*48];
    float xcv = pxc[(size_t)j*48];
    float4 b0 = *(const float4*)(pbc + (size_t)j*16);
    float4 b1 = *(const float4*)(pbc + (size_t)j*16 + 4);
    float Bs[8] = {b0.x,b0.y,b0.z,b0.w,b1.x,b1.y,b1.z,b1.w};
    float dx = dtv*xcv;
    #pragma unroll
    for (int s = 0; s < 8; s++){
      float dA = __expf(dtv*A[s]);
      P[s] *= dA;
      S[s] = S[s]*dA + dx*Bs[s];
    }
  }
  float* out = PS + ((size_t)g*NCH + c)*768 + d*8;
  *(float4*)(out)       = make_float4(P[0],P[1],P[2],P[3]);
  *(float4*)(out+4)     = make_float4(P[4],P[5],P[6],P[7]);
  *(float4*)(out+384)   = make_float4(S[0],S[1],S[2],S[3]);
  *(float4*)(out+388)   = make_float4(S[4],S[5],S[6],S[7]);
}

// ---------------------------------------------------------------------------
// Scan phase 2: per (g, state) sequential over chunks, 8-deep load pipelining.
// Overwrites S-slot with h at chunk start.
// ---------------------------------------------------------------------------
extern "C" __global__ void __launch_bounds__(256)
k_scan2(float* __restrict__ PS)
{
  int t = blockIdx.x*256 + threadIdx.x;
  if (t >= 1536) return;
  int g = t/384, st = t%384;
  float* base = PS + (size_t)g*NCH*768 + st;
  float h = 0.f;
  float Pc[8], Sc[8];
  #pragma unroll
  for (int k = 0; k < 8; k++){ Pc[k]=base[(size_t)k*768]; Sc[k]=base[(size_t)k*768+384]; }
  for (int c0 = 0; c0 < NCH; c0 += 8){
    float Pn[8], Sn[8];
    if (c0 + 8 < NCH){
      #pragma unroll
      for (int k = 0; k < 8; k++){
        Pn[k]=base[(size_t)(c0+8+k)*768];
        Sn[k]=base[(size_t)(c0+8+k)*768+384];
      }
    } else {
      #pragma unroll
      for (int k = 0; k < 8; k++){ Pn[k]=0.f; Sn[k]=0.f; }
    }
    #pragma unroll
    for (int k = 0; k < 8; k++){
      base[(size_t)(c0+k)*768+384] = h;
      h = fmaf(Pc[k], h, Sc[k]);
    }
    #pragma unroll
    for (int k = 0; k < 8; k++){ Pc[k]=Pn[k]; Sc[k]=Sn[k]; }
  }
}

// ---------------------------------------------------------------------------
// Scan phase 3: replay with h0, y = h.C + xc*Dp, gate with silu(z), in-place
// over zb. Same lane=d structure as scan1.
// ---------------------------------------------------------------------------
extern "C" __global__ void __launch_bounds__(192)
k_scan3(const float* __restrict__ dtb, const float* __restrict__ xcb,
        float* __restrict__ zb, const float* __restrict__ BCB,
        const float* __restrict__ A_log, const float* __restrict__ Dp,
        const float* __restrict__ PS, int orient)
{
  const int d = threadIdx.x % 48;
  const int sid = blockIdx.x*4 + threadIdx.x/48;
  const int c = sid & (NCH-1);
  const int g = sid >> 10;
  const int dir = g >> 1;
  const float* Al = A_log + (2*orient+dir)*384 + d*8;
  const float* hp = PS + ((size_t)g*NCH + c)*768 + 384 + d*8;
  float A[8], h[8];
  float4 h0 = *(const float4*)(hp);
  float4 h1 = *(const float4*)(hp+4);
  h[0]=h0.x; h[1]=h0.y; h[2]=h0.z; h[3]=h0.w;
  h[4]=h1.x; h[5]=h1.y; h[6]=h1.z; h[7]=h1.w;
  #pragma unroll
  for (int s = 0; s < 8; s++){ A[s] = -__expf(Al[s]); }
  const float Dpd = Dp[(2*orient+dir)*48 + d];
  const float* pdt = dtb + ROW48(g, c*LC) + d;
  const float* pxc = xcb + ROW48(g, c*LC) + d;
  float*       pz  = zb  + ROW48(g, c*LC) + d;
  const float* pbc = BCB + ROW16(g, c*LC);
  #pragma unroll 4
  for (int j = 0; j < LC; j++){
    float dtv = pdt[(size_t)j*48];
    float xcv = pxc[(size_t)j*48];
    float zv  = pz [(size_t)j*48];
    float4 b0 = *(const float4*)(pbc + (size_t)j*16);
    float4 b1 = *(const float4*)(pbc + (size_t)j*16 + 4);
    float4 c0 = *(const float4*)(pbc + (size_t)j*16 + 8);
    float4 c1 = *(const float4*)(pbc + (size_t)j*16 + 12);
    float Bs[8] = {b0.x,b0.y,b0.z,b0.w,b1.x,b1.y,b1.z,b1.w};
    float Cs[8] = {c0.x,c0.y,c0.z,c0.w,c1.x,c1.y,c1.z,c1.w};
    float dx = dtv*xcv;
    float y = 0.f;
    #pragma unroll
    for (int s = 0; s < 8; s++){
      float dA = __expf(dtv*A[s]);
      h[s] = h[s]*dA + dx*Bs[s];
      y += h[s]*Cs[s];
    }
    y += xcv*Dpd;
    pz[(size_t)j*48] = y * (zv * sigmoidf_(zv));
  }
}

// ---------------------------------------------------------------------------
// out-proj both dirs + un-flip + residual; writes s_out planar [b][48][l].
// ---------------------------------------------------------------------------
extern "C" __global__ void __launch_bounds__(256)
k_combine(const float* __restrict__ yz, const float* __restrict__ out_w,
          const float* __restrict__ resid, float* __restrict__ outp, int orient)
{
  const int tid = threadIdx.x;
  const int b = blockIdx.y;
  const int l = blockIdx.x*256 + tid;
  const int lb2 = LL-1-l;
  const float* owf = out_w + (size_t)(2*orient)*1152;    // (24,48)
  const float* owb = out_w + (size_t)(2*orient+1)*1152;
  float of[24], ob[24];
  {
    float yf[48];
    const float4* rf = (const float4*)(yz + ROW48(b, l));
    #pragma unroll
    for (int k = 0; k < 12; k++){
      float4 v = rf[k];
      yf[4*k]=v.x; yf[4*k+1]=v.y; yf[4*k+2]=v.z; yf[4*k+3]=v.w;
    }
    #pragma unroll
    for (int e = 0; e < 24; e++){
      float acc = 0.f;
      #pragma unroll
      for (int d = 0; d < 48; d++) acc += yf[d]*owf[e*48+d];
      of[e] = acc;
    }
  }
  {
    float yb[48];
    const float4* rb = (const float4*)(yz + ROW48(2+b, lb2));
    #pragma unroll
    for (int k = 0; k < 12; k++){
      float4 v = rb[k];
      yb[4*k]=v.x; yb[4*k+1]=v.y; yb[4*k+2]=v.z; yb[4*k+3]=v.w;
    }
    #pragma unroll
    for (int e = 0; e < 24; e++){
      float acc = 0.f;
      #pragma unroll
      for (int d = 0; d < 48; d++) acc += yb[d]*owb[e*48+d];
      ob[e] = acc;
    }
  }
  const size_t pb = (size_t)b*48*LL + l;
  #pragma unroll
  for (int c2 = 0; c2 < 48; c2++){
    float val = (c2 < 24 ? of[c2] : ob[c2-24]) + resid[pb + (size_t)c2*LL];
    outp[pb + (size_t)c2*LL] = val;
  }
}

// ---------------------------------------------------------------------------
// Digit-rotation transpose: out[t] = in[(t%32)*1024 + (t/32)] per plane,
// optionally + x. Used for l_i -> l_{i+1} and final -> physical (+x).
// ---------------------------------------------------------------------------
extern "C" __global__ void __launch_bounds__(256)
k_perm(const float* __restrict__ in, const float* __restrict__ xadd,
       float* __restrict__ out, int addx)
{
  __shared__ float t[32][33];
  const int q = blockIdx.y;            // plane: b*48 + c
  const float* ip = in + (size_t)q*LL;
  float* op = out + (size_t)q*LL;
  const int ab0 = blockIdx.x*32;
  const int tx = threadIdx.x & 31, ty = threadIdx.x >> 5;
  #pragma unroll
  for (int k = 0; k < 4; k++){
    int c = ty + 8*k;
    t[c][tx] = ip[(size_t)c*1024 + ab0 + tx];
  }
  __syncthreads();
  #pragma unroll
  for (int k = 0; k < 4; k++){
    int ab = ty + 8*k;
    float v = t[tx][ab];
    size_t o = (size_t)(ab0+ab)*32 + tx;
    if (addx) v += xadd[(size_t)q*LL + o];
    op[o] = v;
  }
}

extern "C" void kernel_launch(void* const* d_in, const int* in_sizes, int n_in,
                              void* d_out, int out_size, void* d_ws, size_t ws_size,
                              hipStream_t stream)
{
  const float* x       = (const float*)d_in[0];
  const float* ln_g    = (const float*)d_in[1];
  const float* ln_b    = (const float*)d_in[2];
  const float* in_w    = (const float*)d_in[3];
  const float* conv_w  = (const float*)d_in[4];
  const float* conv_b  = (const float*)d_in[5];
  const float* xproj_w = (const float*)d_in[6];
  const float* dt_w    = (const float*)d_in[7];
  const float* dt_b    = (const float*)d_in[8];
  const float* A_log   = (const float*)d_in[9];
  const float* Dp      = (const float*)d_in[10];
  const float* out_w   = (const float*)d_in[11];
  float* out = (float*)d_out;

  float* ws   = (float*)d_ws;
  float* dtb  = ws;                          // 2*BL48
  float* xcb  = dtb + 2*(size_t)BL48;        // 2*BL48
  float* zbuf = xcb + 2*(size_t)BL48;        // 2*BL48 (y after scan3)
  float* BCB  = zbuf + 2*(size_t)BL48;       // 4*LL*16 = 2.10M
  float* PS   = BCB + (size_t)4*LL*16;       // 4*NCH*768 = 3.15M
  float* sout = PS  + (size_t)4*NCH*768;     // BL48
  float* curT = sout + (size_t)BL48;         // BL48

  for (int i = 0; i < 3; i++){
    const float* ip;
    if (i == 0) ip = x;
    else {
      k_perm<<<dim3(32, 96), 256, 0, stream>>>(sout, x, curT, 0);
      ip = curT;
    }
    k_inconv<<<dim3(LL/128, 2), 128, 0, stream>>>(ip, ln_g + i*48, ln_b + i*48,
        in_w, conv_w, conv_b, xproj_w, dt_w, dt_b, dtb, xcb, zbuf, BCB, i);
    k_scan1<<<dim3(NCH), 192, 0, stream>>>(dtb, xcb, BCB, A_log, PS, i);
    k_scan2<<<dim3(6), 256, 0, stream>>>(PS);
    k_scan3<<<dim3(NCH), 192, 0, stream>>>(dtb, xcb, zbuf, BCB, A_log, Dp, PS, i);
    k_combine<<<dim3(LL/256, 2), 256, 0, stream>>>(zbuf, out_w, ip, sout, i);
  }
  k_perm<<<dim3(32, 96), 256, 0, stream>>>(sout, x, out, 1);
}

// Round 3
// 782.615 us; speedup vs baseline: 3.7000x; 1.3832x over previous
//
#include <hip/hip_runtime.h>
#include <math.h>

// C=48, DM=24, DIN=48, DS=8, DC=4, DTR=2, B=2, D=H=W=32, L=32768
#define LL   32768
#define NCH  1024          // scan chunks per sequence
#define LC   32            // chunk length
#define BL48 3145728       // B*48*L floats (one dir, planar) == 2*48*LL
#define ROW48(g,l) (((size_t)(g)*LL + (l))*48)
#define ROW16(g,l) (((size_t)(g)*LL + (l))*16)

__device__ __forceinline__ float sigmoidf_(float x){ return 1.0f/(1.0f+__expf(-x)); }
__device__ __forceinline__ float softplusf_(float x){ return (x > 20.0f) ? x : log1pf(__expf(x)); }

// ---------------------------------------------------------------------------
// Fused LN + in-proj + causal conv + silu + x-proj + dt(softplus).
// ONE direction per block (blockIdx.z) -> 26 KB LDS -> 2x occupancy.
// Outputs row-major per position: dtb/xcb/zb: [g][l][48], BCB: [g][l][16]
// (B in 0..7, C in 8..15), g = dir*2 + b. Backward written flipped.
// ---------------------------------------------------------------------------
extern "C" __global__ void __launch_bounds__(128)
k_inconv(const float* __restrict__ cur,
         const float* __restrict__ lng, const float* __restrict__ lnb,
         const float* __restrict__ in_w, const float* __restrict__ conv_w,
         const float* __restrict__ conv_b, const float* __restrict__ xproj_w,
         const float* __restrict__ dt_w, const float* __restrict__ dt_b,
         float* __restrict__ dtb, float* __restrict__ xcb, float* __restrict__ zb,
         float* __restrict__ BCB, int orient)
{
  __shared__ float xz[134][49];
  const int tid = threadIdx.x;
  const int b   = blockIdx.y;
  const int dir = blockIdx.z;
  const int bs  = blockIdx.x * 128;
  const int j   = 2*orient + dir;
  const int g   = 2*dir + b;
  const int ch0 = dir*24;
  const float* iw = in_w + j*2304;   // (96,24)

  for (int r = tid; r < 134; r += 128) {
    int l = bs - 3 + r;
    float u[24];
    if (l >= 0 && l < LL) {
      const float* p = cur + (size_t)b*48*LL + l;
      float v[48]; float mu = 0.f;
      #pragma unroll
      for (int c2 = 0; c2 < 48; c2++){ v[c2] = p[(size_t)c2*LL]; mu += v[c2]; }
      mu *= (1.f/48.f);
      float var = 0.f;
      #pragma unroll
      for (int c2 = 0; c2 < 48; c2++){ float dd = v[c2]-mu; var += dd*dd; }
      float rstd = rsqrtf(var*(1.f/48.f) + 1e-5f);
      #pragma unroll
      for (int c2 = 0; c2 < 24; c2++)
        u[c2] = (v[ch0+c2]-mu)*rstd*lng[ch0+c2] + lnb[ch0+c2];
    } else {
      #pragma unroll
      for (int c2 = 0; c2 < 24; c2++) u[c2]=0.f;
    }
    // x-half of in-proj -> LDS (rows with halo)
    for (int e = 0; e < 48; e++){
      float a = 0.f;
      #pragma unroll
      for (int d = 0; d < 24; d++) a += u[d]*iw[e*24+d];
      xz[r][e] = a;
    }
    // z-half -> global rows (own rows only)
    if (r >= 3 && r < 131){
      const int pos = dir ? (LL-1-l) : l;
      float* zr = zb + ROW48(g, pos);
      for (int e0 = 48; e0 < 96; e0 += 4){
        float a[4];
        #pragma unroll
        for (int k = 0; k < 4; k++){
          float s = 0.f;
          #pragma unroll
          for (int d = 0; d < 24; d++) s += u[d]*iw[(e0+k)*24+d];
          a[k]=s;
        }
        *(float4*)(zr + (e0-48)) = make_float4(a[0],a[1],a[2],a[3]);
      }
    }
  }
  __syncthreads();

  const int l   = bs + tid;
  const int pos = dir ? (LL-1-l) : l;
  const float* cw = conv_w + j*192;   // (48,4)
  const float* cb = conv_b + j*48;
  const float* xw = xproj_w + j*864;  // (18,48)
  float xd[18];
  #pragma unroll
  for (int q = 0; q < 18; q++) xd[q]=0.f;
  float* xcr = xcb + ROW48(g, pos);
  for (int d0 = 0; d0 < 48; d0 += 4){
    float vv[4];
    #pragma unroll
    for (int k = 0; k < 4; k++){
      int d = d0 + k;
      float acc = cb[d];
      #pragma unroll
      for (int kk = 0; kk < 4; kk++){
        int rr = dir ? (tid+6-kk) : (tid+kk);
        acc += xz[rr][d] * cw[d*4+kk];
      }
      acc = acc * sigmoidf_(acc);   // silu
      vv[k] = acc;
      #pragma unroll
      for (int q = 0; q < 18; q++) xd[q] += acc*xw[q*48+d];
    }
    *(float4*)(xcr + d0) = make_float4(vv[0],vv[1],vv[2],vv[3]);
  }
  // dt row
  const float* dw = dt_w + j*96;  // (48,2)
  const float* db = dt_b + j*48;
  float* dtr = dtb + ROW48(g, pos);
  for (int d0 = 0; d0 < 48; d0 += 4){
    float vv[4];
    #pragma unroll
    for (int k = 0; k < 4; k++){
      int d = d0 + k;
      vv[k] = softplusf_(xd[0]*dw[d*2] + xd[1]*dw[d*2+1] + db[d]);
    }
    *(float4*)(dtr + d0) = make_float4(vv[0],vv[1],vv[2],vv[3]);
  }
  // B/C row (B = xd[2..9], C = xd[10..17])
  float* bc = BCB + ROW16(g, pos);
  *(float4*)(bc+0)  = make_float4(xd[2],xd[3],xd[4],xd[5]);
  *(float4*)(bc+4)  = make_float4(xd[6],xd[7],xd[8],xd[9]);
  *(float4*)(bc+8)  = make_float4(xd[10],xd[11],xd[12],xd[13]);
  *(float4*)(bc+12) = make_float4(xd[14],xd[15],xd[16],xd[17]);
}

// ---------------------------------------------------------------------------
// Scan phase 1: lane = d (48 per stream), 4 streams per block (block=192).
// Per (g, chunk): P[s]=prod dA, S[s]=local scan from 0. PS layout [g][c][768]:
// P at [d*8+s], S at [384+d*8+s].
// ---------------------------------------------------------------------------
extern "C" __global__ void __launch_bounds__(192)
k_scan1(const float* __restrict__ dtb, const float* __restrict__ xcb,
        const float* __restrict__ BCB, const float* __restrict__ A_log,
        float* __restrict__ PS, int orient)
{
  const int d = threadIdx.x % 48;
  const int sid = blockIdx.x*4 + threadIdx.x/48;
  const int c = sid & (NCH-1);
  const int g = sid >> 10;          // dir*2 + b
  const int dir = g >> 1;
  const float* Al = A_log + (2*orient+dir)*384 + d*8;
  float A[8], P[8], S[8];
  #pragma unroll
  for (int s = 0; s < 8; s++){ A[s] = -__expf(Al[s]); P[s]=1.f; S[s]=0.f; }
  const float* pdt = dtb + ROW48(g, c*LC) + d;
  const float* pxc = xcb + ROW48(g, c*LC) + d;
  const float* pbc = BCB + ROW16(g, c*LC);
  #pragma unroll 4
  for (int j = 0; j < LC; j++){
    float dtv = pdt[(size_t)j*48];
    float xcv = pxc[(size_t)j*48];
    float4 b0 = *(const float4*)(pbc + (size_t)j*16);
    float4 b1 = *(const float4*)(pbc + (size_t)j*16 + 4);
    float Bs[8] = {b0.x,b0.y,b0.z,b0.w,b1.x,b1.y,b1.z,b1.w};
    float dx = dtv*xcv;
    #pragma unroll
    for (int s = 0; s < 8; s++){
      float dA = __expf(dtv*A[s]);
      P[s] *= dA;
      S[s] = S[s]*dA + dx*Bs[s];
    }
  }
  float* out = PS + ((size_t)g*NCH + c)*768 + d*8;
  *(float4*)(out)       = make_float4(P[0],P[1],P[2],P[3]);
  *(float4*)(out+4)     = make_float4(P[4],P[5],P[6],P[7]);
  *(float4*)(out+384)   = make_float4(S[0],S[1],S[2],S[3]);
  *(float4*)(out+388)   = make_float4(S[4],S[5],S[6],S[7]);
}

// ---------------------------------------------------------------------------
// Scan phase 2: per (g, state) sequential over chunks, 8-deep load pipelining.
// Overwrites S-slot with h at chunk start.
// ---------------------------------------------------------------------------
extern "C" __global__ void __launch_bounds__(256)
k_scan2(float* __restrict__ PS)
{
  int t = blockIdx.x*256 + threadIdx.x;
  if (t >= 1536) return;
  int g = t/384, st = t%384;
  float* base = PS + (size_t)g*NCH*768 + st;
  float h = 0.f;
  float Pc[8], Sc[8];
  #pragma unroll
  for (int k = 0; k < 8; k++){ Pc[k]=base[(size_t)k*768]; Sc[k]=base[(size_t)k*768+384]; }
  for (int c0 = 0; c0 < NCH; c0 += 8){
    float Pn[8], Sn[8];
    if (c0 + 8 < NCH){
      #pragma unroll
      for (int k = 0; k < 8; k++){
        Pn[k]=base[(size_t)(c0+8+k)*768];
        Sn[k]=base[(size_t)(c0+8+k)*768+384];
      }
    } else {
      #pragma unroll
      for (int k = 0; k < 8; k++){ Pn[k]=0.f; Sn[k]=0.f; }
    }
    #pragma unroll
    for (int k = 0; k < 8; k++){
      base[(size_t)(c0+k)*768+384] = h;
      h = fmaf(Pc[k], h, Sc[k]);
    }
    #pragma unroll
    for (int k = 0; k < 8; k++){ Pc[k]=Pn[k]; Sc[k]=Sn[k]; }
  }
}

// ---------------------------------------------------------------------------
// Scan phase 3 + gate + out-proj + residual, fused.
// Block = 192 threads = 4 pair-groups of 48 lanes (lane = d).
// Group pr handles fwd chunk cf = 4*bx+pr (plane g=b) AND bwd chunk
// NCH-1-cf (plane g=2+b) — both cover output l in [128*bx+32*pr, +32).
// Gated y staged in LDS; phase C does out-proj over both dirs + resid and
// writes sout planar [b][48][l].
// ---------------------------------------------------------------------------
extern "C" __global__ void __launch_bounds__(192)
k_scan3c(const float* __restrict__ dtb, const float* __restrict__ xcb,
         const float* __restrict__ zb, const float* __restrict__ BCB,
         const float* __restrict__ A_log, const float* __restrict__ Dp,
         const float* __restrict__ PS, const float* __restrict__ out_w,
         const float* __restrict__ resid, float* __restrict__ outp, int orient)
{
  __shared__ float yf[4][32][49];
  __shared__ float yb[4][32][49];
  const int t = threadIdx.x;
  const int d  = t % 48;
  const int pr = t / 48;
  const int b  = blockIdx.y;
  const int bx = blockIdx.x;
  const int cf = bx*4 + pr;
  const int cbk = NCH-1-cf;

  // ---- fwd scan (plane g=b, chunk cf) ----
  {
    const int g = b;
    const float* Al = A_log + (2*orient)*384 + d*8;
    const float* hp = PS + ((size_t)g*NCH + cf)*768 + 384 + d*8;
    float A[8], h[8];
    float4 h0 = *(const float4*)(hp);
    float4 h1 = *(const float4*)(hp+4);
    h[0]=h0.x; h[1]=h0.y; h[2]=h0.z; h[3]=h0.w;
    h[4]=h1.x; h[5]=h1.y; h[6]=h1.z; h[7]=h1.w;
    #pragma unroll
    for (int s = 0; s < 8; s++) A[s] = -__expf(Al[s]);
    const float Dpd = Dp[(2*orient)*48 + d];
    const float* pdt = dtb + ROW48(g, cf*LC) + d;
    const float* pxc = xcb + ROW48(g, cf*LC) + d;
    const float* pz  = zb  + ROW48(g, cf*LC) + d;
    const float* pbc = BCB + ROW16(g, cf*LC);
    for (int j2 = 0; j2 < LC; j2++){
      float dtv = pdt[(size_t)j2*48];
      float xcv = pxc[(size_t)j2*48];
      float zv  = pz [(size_t)j2*48];
      float4 b0 = *(const float4*)(pbc + (size_t)j2*16);
      float4 b1 = *(const float4*)(pbc + (size_t)j2*16 + 4);
      float4 c0 = *(const float4*)(pbc + (size_t)j2*16 + 8);
      float4 c1 = *(const float4*)(pbc + (size_t)j2*16 + 12);
      float Bs[8] = {b0.x,b0.y,b0.z,b0.w,b1.x,b1.y,b1.z,b1.w};
      float Cs[8] = {c0.x,c0.y,c0.z,c0.w,c1.x,c1.y,c1.z,c1.w};
      float dx = dtv*xcv;
      float y = 0.f;
      #pragma unroll
      for (int s = 0; s < 8; s++){
        float dA = __expf(dtv*A[s]);
        h[s] = h[s]*dA + dx*Bs[s];
        y += h[s]*Cs[s];
      }
      y += xcv*Dpd;
      yf[pr][j2][d] = y * (zv * sigmoidf_(zv));
    }
  }
  // ---- bwd scan (plane g=2+b, chunk cbk), stored output-reversed ----
  {
    const int g = 2 + b;
    const float* Al = A_log + (2*orient+1)*384 + d*8;
    const float* hp = PS + ((size_t)g*NCH + cbk)*768 + 384 + d*8;
    float A[8], h[8];
    float4 h0 = *(const float4*)(hp);
    float4 h1 = *(const float4*)(hp+4);
    h[0]=h0.x; h[1]=h0.y; h[2]=h0.z; h[3]=h0.w;
    h[4]=h1.x; h[5]=h1.y; h[6]=h1.z; h[7]=h1.w;
    #pragma unroll
    for (int s = 0; s < 8; s++) A[s] = -__expf(Al[s]);
    const float Dpd = Dp[(2*orient+1)*48 + d];
    const float* pdt = dtb + ROW48(g, cbk*LC) + d;
    const float* pxc = xcb + ROW48(g, cbk*LC) + d;
    const float* pz  = zb  + ROW48(g, cbk*LC) + d;
    const float* pbc = BCB + ROW16(g, cbk*LC);
    for (int j2 = 0; j2 < LC; j2++){
      float dtv = pdt[(size_t)j2*48];
      float xcv = pxc[(size_t)j2*48];
      float zv  = pz [(size_t)j2*48];
      float4 b0 = *(const float4*)(pbc + (size_t)j2*16);
      float4 b1 = *(const float4*)(pbc + (size_t)j2*16 + 4);
      float4 c0 = *(const float4*)(pbc + (size_t)j2*16 + 8);
      float4 c1 = *(const float4*)(pbc + (size_t)j2*16 + 12);
      float Bs[8] = {b0.x,b0.y,b0.z,b0.w,b1.x,b1.y,b1.z,b1.w};
      float Cs[8] = {c0.x,c0.y,c0.z,c0.w,c1.x,c1.y,c1.z,c1.w};
      float dx = dtv*xcv;
      float y = 0.f;
      #pragma unroll
      for (int s = 0; s < 8; s++){
        float dA = __expf(dtv*A[s]);
        h[s] = h[s]*dA + dx*Bs[s];
        y += h[s]*Cs[s];
      }
      y += xcv*Dpd;
      yb[pr][31-j2][d] = y * (zv * sigmoidf_(zv));   // bwd pos -> output-local slot
    }
  }
  __syncthreads();

  // ---- phase C: out-proj both dirs + residual, planar write ----
  if (t < 128){
    const int pair = t >> 5, pp = t & 31;
    const int l = bx*128 + t;
    const float* owf = out_w + (size_t)(2*orient)*1152;    // (24,48)
    const float* owb = out_w + (size_t)(2*orient+1)*1152;
    float of[24], ob[24];
    #pragma unroll
    for (int e = 0; e < 24; e++){ of[e]=0.f; ob[e]=0.f; }
    for (int dd = 0; dd < 48; dd++){
      float vf = yf[pair][pp][dd];
      float vb = yb[pair][pp][dd];
      #pragma unroll
      for (int e = 0; e < 24; e++){
        of[e] += vf*owf[e*48+dd];
        ob[e] += vb*owb[e*48+dd];
      }
    }
    const size_t pb = (size_t)b*48*LL + l;
    #pragma unroll
    for (int c2 = 0; c2 < 48; c2++){
      float val = (c2 < 24 ? of[c2] : ob[c2-24]) + resid[pb + (size_t)c2*LL];
      outp[pb + (size_t)c2*LL] = val;
    }
  }
}

// ---------------------------------------------------------------------------
// Digit-rotation transpose: out[t] = in[(t%32)*1024 + (t/32)] per plane,
// optionally + x. Used for l_i -> l_{i+1} and final -> physical (+x).
// ---------------------------------------------------------------------------
extern "C" __global__ void __launch_bounds__(256)
k_perm(const float* __restrict__ in, const float* __restrict__ xadd,
       float* __restrict__ out, int addx)
{
  __shared__ float t[32][33];
  const int q = blockIdx.y;            // plane: b*48 + c
  const float* ip = in + (size_t)q*LL;
  float* op = out + (size_t)q*LL;
  const int ab0 = blockIdx.x*32;
  const int tx = threadIdx.x & 31, ty = threadIdx.x >> 5;
  #pragma unroll
  for (int k = 0; k < 4; k++){
    int c = ty + 8*k;
    t[c][tx] = ip[(size_t)c*1024 + ab0 + tx];
  }
  __syncthreads();
  #pragma unroll
  for (int k = 0; k < 4; k++){
    int ab = ty + 8*k;
    float v = t[tx][ab];
    size_t o = (size_t)(ab0+ab)*32 + tx;
    if (addx) v += xadd[(size_t)q*LL + o];
    op[o] = v;
  }
}

extern "C" void kernel_launch(void* const* d_in, const int* in_sizes, int n_in,
                              void* d_out, int out_size, void* d_ws, size_t ws_size,
                              hipStream_t stream)
{
  const float* x       = (const float*)d_in[0];
  const float* ln_g    = (const float*)d_in[1];
  const float* ln_b    = (const float*)d_in[2];
  const float* in_w    = (const float*)d_in[3];
  const float* conv_w  = (const float*)d_in[4];
  const float* conv_b  = (const float*)d_in[5];
  const float* xproj_w = (const float*)d_in[6];
  const float* dt_w    = (const float*)d_in[7];
  const float* dt_b    = (const float*)d_in[8];
  const float* A_log   = (const float*)d_in[9];
  const float* Dp      = (const float*)d_in[10];
  const float* out_w   = (const float*)d_in[11];
  float* out = (float*)d_out;

  float* ws   = (float*)d_ws;
  float* dtb  = ws;                          // 4 planes * LL * 48
  float* xcb  = dtb + 2*(size_t)BL48;
  float* zbuf = xcb + 2*(size_t)BL48;
  float* BCB  = zbuf + 2*(size_t)BL48;       // 4*LL*16
  float* PS   = BCB + (size_t)4*LL*16;       // 4*NCH*768
  float* sout = PS  + (size_t)4*NCH*768;     // BL48
  float* curT = sout + (size_t)BL48;         // BL48

  for (int i = 0; i < 3; i++){
    const float* ip;
    if (i == 0) ip = x;
    else {
      k_perm<<<dim3(32, 96), 256, 0, stream>>>(sout, x, curT, 0);
      ip = curT;
    }
    k_inconv<<<dim3(LL/128, 2, 2), 128, 0, stream>>>(ip, ln_g + i*48, ln_b + i*48,
        in_w, conv_w, conv_b, xproj_w, dt_w, dt_b, dtb, xcb, zbuf, BCB, i);
    k_scan1<<<dim3(NCH), 192, 0, stream>>>(dtb, xcb, BCB, A_log, PS, i);
    k_scan2<<<dim3(6), 256, 0, stream>>>(PS);
    k_scan3c<<<dim3(NCH/4, 2), 192, 0, stream>>>(dtb, xcb, zbuf, BCB, A_log, Dp,
        PS, out_w, ip, sout, i);
  }
  k_perm<<<dim3(32, 96), 256, 0, stream>>>(sout, x, out, 1);
}